// Round 1
// baseline (5113.503 us; speedup 1.0000x reference)
//
#include <hip/hip_runtime.h>

// ============================================================================
// 2-layer LSTM (B=64,T=512,I=256,H=1024) + head. Persistent kernel, R6.
//
// R6 vs R5 (9.46 us/step; MfmaUtil 7.4%, 85% idle => exposed sync chain):
//  * PER-WG FLAGS, no atomic aggregation: all h-exchange is within a
//    (lay,bg) group of 32 WGs. Producer wave 0: pack -> vstore16 ->
//    s_waitcnt vmcnt(0) -> single flag store. Consumers: 32 lanes poll 32
//    producer flags IN PARALLEL (wave 1), then __syncthreads. Removes 2
//    atomic MALL RTTs + the full-block drain barrier per step per layer.
//  * FULL-DEPTH A PREFETCH: all 4-5 h-fragments (MALL, ~0.4-0.9us latency)
//    issued upfront after the spin -> 1 exposed RTT per phase, not ~4.
//    (MFMA burst per chunk ~40cy can't hide a MALL RTT at 2-deep.)
//  * L1 PHASE SWAP: phase B (h2(n-1), own-gate: almost always satisfied)
//    runs FIRST; fresh h0(n) gate second. First-chunk B-frags (static
//    weights) prefetch before each spin.
//  * gbufT stride 20 -> 24: reduce-read hh-offsets {0,24,16,8} mod 32 =
//    exactly 2 lanes/bank (free, m136) vs 3-way before; dump uniform.
//    SQ_LDS_BANK_CONFLICT predicted 2.7e8 -> ~1e8.
//
// Workspace (44,834,816 B):
//   0         W0p  fp16 [32 cs][40 c][8 nt][512]   10,485,760
//   10485760  W1p  fp16 [32 cs][64 c][8 nt][512]   16,777,216
//   27262976  h0q  fp16 4 slots x [32 c][4 bg][512]   524,288
//   27787264  h2q  fp16 2 slots x same                262,144
//   28049408  sync uint[2048]: flag[lay][bg][cs] stride 8   8,192
//   28057600  xpk  fp16 [512 t][8 c][4 bg][512]    16,777,216
// ============================================================================

typedef _Float16 h8 __attribute__((ext_vector_type(8)));
typedef float    f4 __attribute__((ext_vector_type(4)));
typedef unsigned long long u64;

#define WS_W0P   0
#define WS_W1P   10485760
#define WS_H0Q   27262976
#define WS_H2Q   27787264
#define WS_SYNC  28049408
#define WS_XPK   28057600
#define WS_XPK_END 44834816ULL

static __device__ __forceinline__ float sigm(float v) { return 1.f / (1.f + __expf(-v)); }
static __device__ __forceinline__ float tanh_fast(float v) {
  const float e = __expf(2.f * v);
  return 1.f - 2.f / (e + 1.f);
}
static __device__ __forceinline__ h8 vload16(const _Float16* p) {
  return *(const volatile h8*)p;          // coherent (MALL) 16B load
}
static __device__ __forceinline__ void vstore16(_Float16* p, h8 v) {
  *(volatile h8*)p = v;                   // coherent (MALL) 16B store
}

// ---------------------------------------------------------------------------
__global__ void prep_kernel(const float* __restrict__ x,
                            const float* __restrict__ Wih0, const float* __restrict__ Whh0,
                            const float* __restrict__ Wih1, const float* __restrict__ Whh1,
                            _Float16* __restrict__ W0p, _Float16* __restrict__ W1p,
                            _Float16* __restrict__ xpk,
                            unsigned* __restrict__ hz, unsigned* __restrict__ sync_ws)
{
  const long tid0 = (long)blockIdx.x * blockDim.x + threadIdx.x;
  const long np   = (long)gridDim.x * blockDim.x;

  // W0p: e = ((cs*40 + c)*8 + nt)*512 + l15*32 + quad*8 + j
  for (long e = tid0; e < 5242880; e += np) {
    const int j = e & 7, quad = (e >> 3) & 3, l15 = (e >> 5) & 15, nt = (e >> 9) & 7;
    const int r = (int)(e >> 12);
    const int c = r % 40, cs = r / 40;
    const int col = nt * 16 + l15;
    const int row = (col >> 5) * 1024 + cs * 32 + (col & 31);
    const int k = c * 32 + quad * 8 + j;
    const float v = (k < 256) ? Wih0[(long)row * 256 + k] : Whh0[(long)row * 1024 + k - 256];
    W0p[e] = (_Float16)v;
  }
  // W1p: r = cs*64 + c
  for (long e = tid0; e < 8388608; e += np) {
    const int j = e & 7, quad = (e >> 3) & 3, l15 = (e >> 5) & 15, nt = (e >> 9) & 7;
    const int r = (int)(e >> 12);
    const int c = r & 63, cs = r >> 6;
    const int col = nt * 16 + l15;
    const int row = (col >> 5) * 1024 + cs * 32 + (col & 31);
    const int k = c * 32 + quad * 8 + j;
    const float v = (k < 1024) ? Wih1[(long)row * 1024 + k] : Whh1[(long)row * 1024 + k - 1024];
    W1p[e] = (_Float16)v;
  }
  // xpk: e = ((t*8 + c)*4 + bg)*512 + b16*32 + k32
  if (xpk) {
    for (long e = tid0; e < 8388608; e += np) {
      const int k32 = e & 31, b16 = (e >> 5) & 15, bg = (e >> 9) & 3;
      const int c = (e >> 11) & 7;
      const int t = (int)(e >> 14);
      const int b = bg * 16 + b16, k = c * 32 + k32;
      xpk[e] = (_Float16)x[(long)b * 131072 + (long)t * 256 + k];
    }
  }
  for (long e = tid0; e < 196608; e += np) hz[e] = 0u;   // h0q + h2q
  if (tid0 < 2048) sync_ws[tid0] = 0u;
}

// ---------------------------------------------------------------------------
// sync layout (uint idx): flag for WG (lay,bg,cs) at ((lay*4+bg)*32 + cs)*8.
// Flag value = n+1 once that WG's h(n) slice is visible at MALL.
// ---------------------------------------------------------------------------
template<bool XP>
__launch_bounds__(512, 1)
__global__ void lstm_kernel(const float* __restrict__ x, const _Float16* __restrict__ xpk,
                            const float* __restrict__ bih0, const float* __restrict__ bhh0,
                            const float* __restrict__ bih1, const float* __restrict__ bhh1,
                            const _Float16* __restrict__ W0p, const _Float16* __restrict__ W1p,
                            _Float16* __restrict__ h0q, _Float16* __restrict__ h2q,
                            unsigned* __restrict__ sy)
{
  extern __shared__ float gb[];                    // gbufT [8][128][24] = 98,304 B
  __shared__ float cst[512];                       // c-state, slot = tid (hh*16+b16)
  __shared__ float biasl[128];
  __shared__ _Float16 htmp[32 * 18];               // [hh][b16] pad 18

  const int tid = threadIdx.x, wg = blockIdx.x;
  const int xcd = wg & 7, jdec = wg >> 3;
  const int lay = jdec & 1, jj = jdec >> 1;
  const int bg = jj & 3, csl = jj >> 2;
  const int cs = xcd * 4 + csl;                    // col-slice 0..31 (XCD-local)
  const int lane = tid & 63, kg = tid >> 6;
  const int l15 = lane & 15, quad = lane >> 4;
  const int boff = l15 * 32 + quad * 8;            // B-frag offset in 1024-blk
  const int aoff = bg * 512 + l15 * 32 + quad * 8; // A-frag offset in 2048-blk

  const _Float16* Wp = lay ? (W1p + (long)cs * 262144) : (W0p + (long)cs * 163840);

  if (tid < 128) {
    const int row = (tid >> 5) * 1024 + cs * 32 + (tid & 31);
    biasl[tid] = lay ? (bih1[row] + bhh1[row]) : (bih0[row] + bhh0[row]);
  }
  cst[tid] = 0.f;
  __syncthreads();

  unsigned* const fL0  = sy + (bg * 32) * 8;             // layer-0 flags, this bg
  unsigned* const fL1  = sy + ((4 + bg) * 32) * 8;       // layer-1 flags, this bg
  unsigned* const fOwn = (lay ? fL1 : fL0) + cs * 8;     // this WG's flag

  auto spin = [&](const unsigned* p, int tgt) {
    if (tgt <= 0) return;
    while ((int)__hip_atomic_load(p, __ATOMIC_RELAXED, __HIP_MEMORY_SCOPE_AGENT) < tgt)
      __builtin_amdgcn_s_sleep(1);
  };

  auto dump = [&](const f4* acc) {
#pragma unroll
    for (int nt = 0; nt < 8; ++nt)
      *(f4*)&gb[(kg * 128 + nt * 16 + l15) * 24 + quad * 4] = acc[nt];
  };

  auto pointwise_publish = [&](_Float16* wr, int n) {
    __syncthreads();                               // gbufT complete
    {
      const int b16 = tid & 15, hh = tid >> 4;
      float gv[4];
#pragma unroll
      for (int gt = 0; gt < 4; ++gt) {
        float s = biasl[gt * 32 + hh];
#pragma unroll
        for (int k = 0; k < 8; ++k) s += gb[(k * 128 + gt * 32 + hh) * 24 + b16];
        gv[gt] = s;
      }
      const float si = sigm(gv[0]), sf = sigm(gv[1]);
      const float tg = tanh_fast(gv[2]), so = sigm(gv[3]);
      const float cn = sf * cst[tid] + si * tg;
      cst[tid] = cn;
      htmp[hh * 18 + b16] = (_Float16)(so * tanh_fast(cn));
    }
    __syncthreads();                               // htmp complete; waves 1-7 run ahead
    if (tid < 64) {                                // wave 0: pack + publish + flag
      const int b16 = tid & 15, q = tid >> 4;
      union { h8 v; _Float16 e[8]; } r;
#pragma unroll
      for (int i = 0; i < 8; ++i) r.e[i] = htmp[(q * 8 + i) * 18 + b16];
      vstore16(wr + (cs * 4 + bg) * 512 + b16 * 32 + q * 8, r.v);
      asm volatile("s_waitcnt vmcnt(0)" ::: "memory");   // wave-local drain (all 64 lanes)
      if (tid == 0)
        __hip_atomic_store(fOwn, (unsigned)(n + 1),
                           __ATOMIC_RELAXED, __HIP_MEMORY_SCOPE_AGENT);
    }
  };

  if (lay == 0) {
    const int c0 = kg * 5;
    for (int n = 0; n < 512; ++n) {
      const _Float16* h0prev = h0q + ((n - 1) & 3) * 65536;
      const _Float16* xs = XP ? (xpk + (long)n * 16384) : nullptr;

      f4 acc[8] = {};
      h8 Ab[5]; h8 Bb[2][8];
      auto loadB = [&](int c, int sl) {
        const _Float16* bp = Wp + (long)c * 4096 + boff;
#pragma unroll
        for (int nt = 0; nt < 8; ++nt) Bb[sl][nt] = *(const h8*)(bp + nt * 512);
      };
      auto loadA = [&](int c, int idx) {
        if (c < 8) {
          if (XP) Ab[idx] = *(const h8*)(xs + c * 2048 + aoff);
          else {
            const float* q = x + (long)(bg * 16 + l15) * 131072 + (long)n * 256 + c * 32 + quad * 8;
            const f4 v0 = *(const f4*)q;
            const f4 v1 = *(const f4*)(q + 4);
            h8 t;
            t[0]=(_Float16)v0[0]; t[1]=(_Float16)v0[1]; t[2]=(_Float16)v0[2]; t[3]=(_Float16)v0[3];
            t[4]=(_Float16)v1[0]; t[5]=(_Float16)v1[1]; t[6]=(_Float16)v1[2]; t[7]=(_Float16)v1[3];
            Ab[idx] = t;
          }
        } else {
          Ab[idx] = vload16(h0prev + (c - 8) * 2048 + aoff);
        }
      };

      loadB(c0, 0);                                // static weights: pre-spin
#pragma unroll
      for (int i = 0; i < 5; ++i)
        if (c0 + i < 8) loadA(c0 + i, i);          // x-chunks: no dependency

      if (kg == 1) {                               // wave 1 polls (parallel lanes)
        if (lane < 32) spin(fL0 + lane * 8, n);           // h0(n-1) visible
        else           spin(fL1 + (lane - 32) * 8, n - 3);// slot n&3 consumed
      }
      __syncthreads();

#pragma unroll
      for (int i = 0; i < 5; ++i)
        if (c0 + i >= 8) loadA(c0 + i, i);         // all h-frags in flight at once

#pragma unroll
      for (int i = 0; i < 5; ++i) {
        if (i + 1 < 5) loadB(c0 + i + 1, (i + 1) & 1);
        const h8 A = Ab[i];
#pragma unroll
        for (int nt = 0; nt < 8; ++nt)
          acc[nt] = __builtin_amdgcn_mfma_f32_16x16x32_f16(A, Bb[i & 1][nt], acc[nt], 0, 0, 0);
      }
      dump(acc);
      pointwise_publish(h0q + (n & 3) * 65536, n);
    }
  } else {
    const int c0 = kg * 4;
    for (int n = 0; n < 512; ++n) {
      const _Float16* h0cur  = h0q + (n & 3) * 65536;
      const _Float16* h2prev = h2q + ((n - 1) & 1) * 65536;

      f4 acc[8] = {};
      h8 Ab[4]; h8 Bb[2][8];
      auto loadB = [&](int c, int sl) {
        const _Float16* bp = Wp + (long)c * 4096 + boff;
#pragma unroll
        for (int nt = 0; nt < 8; ++nt) Bb[sl][nt] = *(const h8*)(bp + nt * 512);
      };
      auto loadA = [&](const _Float16* hb, int cloc, int idx) {
        Ab[idx] = vload16(hb + cloc * 2048 + aoff);
      };

      // ---- phase B FIRST: h2(n-1) part (weights 32+c) — own-gate usually ready
      loadB(32 + c0, 0);                           // pre-spin weight prefetch
      if (kg == 1) {
        if (lane < 32) spin(fL1 + lane * 8, n);    // h2(n-1) visible (also slot-free)
      }
      __syncthreads();
#pragma unroll
      for (int i = 0; i < 4; ++i) loadA(h2prev, c0 + i, i);
#pragma unroll
      for (int i = 0; i < 4; ++i) {
        if (i + 1 < 4) loadB(32 + c0 + i + 1, (i + 1) & 1);
        const h8 A = Ab[i];
#pragma unroll
        for (int nt = 0; nt < 8; ++nt)
          acc[nt] = __builtin_amdgcn_mfma_f32_16x16x32_f16(A, Bb[i & 1][nt], acc[nt], 0, 0, 0);
      }

      // ---- phase A: h0(n) part (weights c) — fresh cross-layer gate
      loadB(c0, 0);                                // pre-spin weight prefetch
      if (kg == 1) {
        if (lane < 32) spin(fL0 + lane * 8, n + 1);// h0(n) visible
      }
      __syncthreads();
#pragma unroll
      for (int i = 0; i < 4; ++i) loadA(h0cur, c0 + i, i);
#pragma unroll
      for (int i = 0; i < 4; ++i) {
        if (i + 1 < 4) loadB(c0 + i + 1, (i + 1) & 1);
        const h8 A = Ab[i];
#pragma unroll
        for (int nt = 0; nt < 8; ++nt)
          acc[nt] = __builtin_amdgcn_mfma_f32_16x16x32_f16(A, Bb[i & 1][nt], acc[nt], 0, 0, 0);
      }
      dump(acc);
      pointwise_publish(h2q + (n & 1) * 65536, n);
    }
  }
}

// ---------------------------------------------------------------------------
__global__ void head_kernel(const _Float16* __restrict__ h2s, const float* __restrict__ Wh,
                            const float* __restrict__ bh, float* __restrict__ out)
{
  const int blk = blockIdx.x;            // 64*24
  const int b = blk / 24, j = blk % 24;
  const int lane = threadIdx.x;          // 64
  float sum = 0.f;
#pragma unroll
  for (int k0 = 0; k0 < 1024; k0 += 64) {
    const int hid = k0 + lane;
    const float hv = (float)h2s[((hid >> 5) * 4 + (b >> 4)) * 512 + (b & 15) * 32 + (hid & 31)];
    sum += hv * Wh[(long)j * 1024 + hid];
  }
#pragma unroll
  for (int off = 32; off > 0; off >>= 1)
    sum += __shfl_down(sum, off, 64);
  if (lane == 0) out[b * 24 + j] = sum + bh[j];
}

// ---------------------------------------------------------------------------
extern "C" void kernel_launch(void* const* d_in, const int* in_sizes, int n_in,
                              void* d_out, int out_size, void* d_ws, size_t ws_size,
                              hipStream_t stream)
{
  const float* x    = (const float*)d_in[0];
  const float* Wih0 = (const float*)d_in[1];
  const float* Whh0 = (const float*)d_in[2];
  const float* bih0 = (const float*)d_in[3];
  const float* bhh0 = (const float*)d_in[4];
  const float* Wih1 = (const float*)d_in[5];
  const float* Whh1 = (const float*)d_in[6];
  const float* bih1 = (const float*)d_in[7];
  const float* bhh1 = (const float*)d_in[8];
  const float* Whd  = (const float*)d_in[9];
  const float* bhd  = (const float*)d_in[10];

  char* ws = (char*)d_ws;
  _Float16* W0p     = (_Float16*)(ws + WS_W0P);
  _Float16* W1p     = (_Float16*)(ws + WS_W1P);
  _Float16* h0q     = (_Float16*)(ws + WS_H0Q);
  _Float16* h2q     = (_Float16*)(ws + WS_H2Q);
  unsigned* sync_ws = (unsigned*)(ws + WS_SYNC);
  float* out = (float*)d_out;

  const bool use_xpk = (ws_size >= WS_XPK_END);
  _Float16* xpk = use_xpk ? (_Float16*)(ws + WS_XPK) : nullptr;

  prep_kernel<<<dim3(2048), dim3(256), 0, stream>>>(
      x, Wih0, Whh0, Wih1, Whh1, W0p, W1p, xpk,
      (unsigned*)(ws + WS_H0Q), sync_ws);

  // static ~3.7 KB + dynamic 98,304 B LDS -> 1 WG/CU -> 256 WGs co-resident.
  if (use_xpk)
    lstm_kernel<true><<<dim3(256), dim3(512), 98304, stream>>>(
        x, xpk, bih0, bhh0, bih1, bhh1, W0p, W1p, h0q, h2q, sync_ws);
  else
    lstm_kernel<false><<<dim3(256), dim3(512), 98304, stream>>>(
        x, nullptr, bih0, bhh0, bih1, bhh1, W0p, W1p, h0q, h2q, sync_ws);

  head_kernel<<<dim3(64 * 24), dim3(64), 0, stream>>>(
      h2q + 65536, Whd, bhd, out);   // h2(511), slot 511&1 = 1
}

// Round 2
// 4563.774 us; speedup vs baseline: 1.1205x; 1.1205x over previous
//
#include <hip/hip_runtime.h>

// ============================================================================
// 2-layer LSTM (B=64,T=512,I=256,H=1024) + head. Persistent kernel, R7.
//
// R7 vs R6 (5114us, regressed from R5's 4843):
//  * REVERT phase swap: phase A (h0(n), usually ready - L0 runs ahead on the
//    4-slot FIFO) FIRST; the h2(n-1) recurrent-chain spin hides behind it.
//  * PER-WAVE point-of-use spins: wave kg polls ONLY the 4-5 producer flags
//    for its own chunk range (lanes in parallel), no spin barrier. Only the
//    two publish barriers (gbuf/htmp) remain per step.
//  * Slot-free gates moved to wave 0 right before the publish store
//    (fL1 >= n-3 for L0, >= n for L1). Same-layer coverage at publish time
//    is implied by barrier1 (all waves passed their producer spins).
//  * Flag layout: one 128-B line per (lay,bg) group = 32 contiguous uints.
//    Consumer poll set = 1 line; no cross-group false sharing.
//  * Keep from R6: producer publish = vstore16 -> s_waitcnt vmcnt(0) ->
//    flag store (no atomic tree, no drain barrier); full-depth A prefetch;
//    pre-spin weight prefetch; gbufT stride 24 (2-way banks, free).
//
// Workspace (44,834,816 B):
//   0         W0p  fp16 [32 cs][40 c][8 nt][512]   10,485,760
//   10485760  W1p  fp16 [32 cs][64 c][8 nt][512]   16,777,216
//   27262976  h0q  fp16 4 slots x [32 c][4 bg][512]   524,288
//   27787264  h2q  fp16 2 slots x same                262,144
//   28049408  sync uint[2048]: flag[(lay*4+bg)*32 + cs], 128B/group  8,192
//   28057600  xpk  fp16 [512 t][8 c][4 bg][512]    16,777,216
// ============================================================================

typedef _Float16 h8 __attribute__((ext_vector_type(8)));
typedef float    f4 __attribute__((ext_vector_type(4)));
typedef unsigned long long u64;

#define WS_W0P   0
#define WS_W1P   10485760
#define WS_H0Q   27262976
#define WS_H2Q   27787264
#define WS_SYNC  28049408
#define WS_XPK   28057600
#define WS_XPK_END 44834816ULL

static __device__ __forceinline__ float sigm(float v) { return 1.f / (1.f + __expf(-v)); }
static __device__ __forceinline__ float tanh_fast(float v) {
  const float e = __expf(2.f * v);
  return 1.f - 2.f / (e + 1.f);
}
static __device__ __forceinline__ h8 vload16(const _Float16* p) {
  return *(const volatile h8*)p;          // coherent (MALL) 16B load
}
static __device__ __forceinline__ void vstore16(_Float16* p, h8 v) {
  *(volatile h8*)p = v;                   // coherent (MALL) 16B store
}

// ---------------------------------------------------------------------------
__global__ void prep_kernel(const float* __restrict__ x,
                            const float* __restrict__ Wih0, const float* __restrict__ Whh0,
                            const float* __restrict__ Wih1, const float* __restrict__ Whh1,
                            _Float16* __restrict__ W0p, _Float16* __restrict__ W1p,
                            _Float16* __restrict__ xpk,
                            unsigned* __restrict__ hz, unsigned* __restrict__ sync_ws)
{
  const long tid0 = (long)blockIdx.x * blockDim.x + threadIdx.x;
  const long np   = (long)gridDim.x * blockDim.x;

  // W0p: e = ((cs*40 + c)*8 + nt)*512 + l15*32 + quad*8 + j
  for (long e = tid0; e < 5242880; e += np) {
    const int j = e & 7, quad = (e >> 3) & 3, l15 = (e >> 5) & 15, nt = (e >> 9) & 7;
    const int r = (int)(e >> 12);
    const int c = r % 40, cs = r / 40;
    const int col = nt * 16 + l15;
    const int row = (col >> 5) * 1024 + cs * 32 + (col & 31);
    const int k = c * 32 + quad * 8 + j;
    const float v = (k < 256) ? Wih0[(long)row * 256 + k] : Whh0[(long)row * 1024 + k - 256];
    W0p[e] = (_Float16)v;
  }
  // W1p: r = cs*64 + c
  for (long e = tid0; e < 8388608; e += np) {
    const int j = e & 7, quad = (e >> 3) & 3, l15 = (e >> 5) & 15, nt = (e >> 9) & 7;
    const int r = (int)(e >> 12);
    const int c = r & 63, cs = r >> 6;
    const int col = nt * 16 + l15;
    const int row = (col >> 5) * 1024 + cs * 32 + (col & 31);
    const int k = c * 32 + quad * 8 + j;
    const float v = (k < 1024) ? Wih1[(long)row * 1024 + k] : Whh1[(long)row * 1024 + k - 1024];
    W1p[e] = (_Float16)v;
  }
  // xpk: e = ((t*8 + c)*4 + bg)*512 + b16*32 + k32
  if (xpk) {
    for (long e = tid0; e < 8388608; e += np) {
      const int k32 = e & 31, b16 = (e >> 5) & 15, bg = (e >> 9) & 3;
      const int c = (e >> 11) & 7;
      const int t = (int)(e >> 14);
      const int b = bg * 16 + b16, k = c * 32 + k32;
      xpk[e] = (_Float16)x[(long)b * 131072 + (long)t * 256 + k];
    }
  }
  for (long e = tid0; e < 196608; e += np) hz[e] = 0u;   // h0q + h2q
  if (tid0 < 2048) sync_ws[tid0] = 0u;
}

// ---------------------------------------------------------------------------
// sync layout (uint idx): flag[(lay*4+bg)*32 + cs]. One 128-B line per
// (lay,bg) group. Flag value = n+1 once that WG's h(n) slice is MALL-visible.
// ---------------------------------------------------------------------------
template<bool XP>
__launch_bounds__(512, 1)
__global__ void lstm_kernel(const float* __restrict__ x, const _Float16* __restrict__ xpk,
                            const float* __restrict__ bih0, const float* __restrict__ bhh0,
                            const float* __restrict__ bih1, const float* __restrict__ bhh1,
                            const _Float16* __restrict__ W0p, const _Float16* __restrict__ W1p,
                            _Float16* __restrict__ h0q, _Float16* __restrict__ h2q,
                            unsigned* __restrict__ sy)
{
  extern __shared__ float gb[];                    // gbufT [8][128][24] = 98,304 B
  __shared__ float cst[512];                       // c-state, slot = tid (hh*16+b16)
  __shared__ float biasl[128];
  __shared__ _Float16 htmp[32 * 18];               // [hh][b16] pad 18

  const int tid = threadIdx.x, wg = blockIdx.x;
  const int xcd = wg & 7, jdec = wg >> 3;
  const int lay = jdec & 1, jj = jdec >> 1;
  const int bg = jj & 3, csl = jj >> 2;
  const int cs = xcd * 4 + csl;                    // col-slice 0..31 (XCD-local)
  const int lane = tid & 63, kg = tid >> 6;
  const int l15 = lane & 15, quad = lane >> 4;
  const int boff = l15 * 32 + quad * 8;            // B-frag offset in 1024-blk
  const int aoff = bg * 512 + l15 * 32 + quad * 8; // A-frag offset in 2048-blk

  const _Float16* Wp = lay ? (W1p + (long)cs * 262144) : (W0p + (long)cs * 163840);

  if (tid < 128) {
    const int row = (tid >> 5) * 1024 + cs * 32 + (tid & 31);
    biasl[tid] = lay ? (bih1[row] + bhh1[row]) : (bih0[row] + bhh0[row]);
  }
  cst[tid] = 0.f;
  __syncthreads();

  unsigned* const fL0  = sy + (bg * 32);           // layer-0 flags, this bg (1 line)
  unsigned* const fL1  = sy + ((4 + bg) * 32);     // layer-1 flags, this bg (1 line)
  unsigned* const fOwn = (lay ? fL1 : fL0) + cs;   // this WG's flag

  auto spin1 = [&](const unsigned* p, int tgt) {   // exits immediately if tgt<=0
    while ((int)__hip_atomic_load(p, __ATOMIC_RELAXED, __HIP_MEMORY_SCOPE_AGENT) < tgt)
      __builtin_amdgcn_s_sleep(2);
  };

  auto dump = [&](const f4* acc) {
#pragma unroll
    for (int nt = 0; nt < 8; ++nt)
      *(f4*)&gb[(kg * 128 + nt * 16 + l15) * 24 + quad * 4] = acc[nt];
  };

  // gate: slot-free flags (fL1), gtgt: required value; polled by wave-0 lanes
  auto pointwise_publish = [&](_Float16* wr, int n, int gtgt) {
    __syncthreads();                               // gbufT complete
    {
      const int b16 = tid & 15, hh = tid >> 4;
      float gv[4];
#pragma unroll
      for (int gt = 0; gt < 4; ++gt) {
        float s = biasl[gt * 32 + hh];
#pragma unroll
        for (int k = 0; k < 8; ++k) s += gb[(k * 128 + gt * 32 + hh) * 24 + b16];
        gv[gt] = s;
      }
      const float si = sigm(gv[0]), sf = sigm(gv[1]);
      const float tg = tanh_fast(gv[2]), so = sigm(gv[3]);
      const float cn = sf * cst[tid] + si * tg;
      cst[tid] = cn;
      htmp[hh * 18 + b16] = (_Float16)(so * tanh_fast(cn));
    }
    __syncthreads();                               // htmp complete; waves 1-7 run ahead
    if (tid < 64) {                                // wave 0: gate + pack + publish + flag
      if (tid < 32) spin1(fL1 + tid, gtgt);        // slot-free (usually satisfied)
      const int b16 = tid & 15, q = tid >> 4;
      union { h8 v; _Float16 e[8]; } r;
#pragma unroll
      for (int i = 0; i < 8; ++i) r.e[i] = htmp[(q * 8 + i) * 18 + b16];
      vstore16(wr + (cs * 4 + bg) * 512 + b16 * 32 + q * 8, r.v);
      asm volatile("s_waitcnt vmcnt(0)" ::: "memory");   // wave-local drain
      if (tid == 0)
        __hip_atomic_store(fOwn, (unsigned)(n + 1),
                           __ATOMIC_RELAXED, __HIP_MEMORY_SCOPE_AGENT);
    }
  };

  if (lay == 0) {
    const int c0 = kg * 5;
    for (int n = 0; n < 512; ++n) {
      const _Float16* h0prev = h0q + ((n - 1) & 3) * 65536;
      const _Float16* xs = XP ? (xpk + (long)n * 16384) : nullptr;

      f4 acc[8] = {};
      h8 Ab[5]; h8 Bb[2][8];
      auto loadB = [&](int c, int sl) {
        const _Float16* bp = Wp + (long)c * 4096 + boff;
#pragma unroll
        for (int nt = 0; nt < 8; ++nt) Bb[sl][nt] = *(const h8*)(bp + nt * 512);
      };
      auto loadA = [&](int c, int idx) {
        if (c < 8) {
          if (XP) Ab[idx] = *(const h8*)(xs + c * 2048 + aoff);
          else {
            const float* q = x + (long)(bg * 16 + l15) * 131072 + (long)n * 256 + c * 32 + quad * 8;
            const f4 v0 = *(const f4*)q;
            const f4 v1 = *(const f4*)(q + 4);
            h8 t;
            t[0]=(_Float16)v0[0]; t[1]=(_Float16)v0[1]; t[2]=(_Float16)v0[2]; t[3]=(_Float16)v0[3];
            t[4]=(_Float16)v1[0]; t[5]=(_Float16)v1[1]; t[6]=(_Float16)v1[2]; t[7]=(_Float16)v1[3];
            Ab[idx] = t;
          }
        } else {
          Ab[idx] = vload16(h0prev + (c - 8) * 2048 + aoff);
        }
      };

      loadB(c0, 0);                                // static weights: pre-spin
#pragma unroll
      for (int i = 0; i < 5; ++i)
        if (c0 + i < 8) loadA(c0 + i, i);          // x-chunks: no dependency

      // per-wave, per-producer spin (lanes poll this wave's needed flags only)
      if (lane < 5) {
        const int c = c0 + lane;
        if (c >= 8) spin1(fL0 + (c - 8), n);       // h0(n-1) slice visible
      }

#pragma unroll
      for (int i = 0; i < 5; ++i)
        if (c0 + i >= 8) loadA(c0 + i, i);         // all h-frags in flight at once

#pragma unroll
      for (int i = 0; i < 5; ++i) {
        if (i + 1 < 5) loadB(c0 + i + 1, (i + 1) & 1);
        const h8 A = Ab[i];
#pragma unroll
        for (int nt = 0; nt < 8; ++nt)
          acc[nt] = __builtin_amdgcn_mfma_f32_16x16x32_f16(A, Bb[i & 1][nt], acc[nt], 0, 0, 0);
      }
      dump(acc);
      // slot n&3 overwrites h0(n-4): L1 consumers (step n-4) done iff fL1 >= n-3.
      pointwise_publish(h0q + (n & 3) * 65536, n, n - 3);
    }
  } else {
    const int c0 = kg * 4;
    for (int n = 0; n < 512; ++n) {
      const _Float16* h0cur  = h0q + (n & 3) * 65536;
      const _Float16* h2prev = h2q + ((n - 1) & 1) * 65536;

      f4 acc[8] = {};
      h8 Ab[4]; h8 Bb[2][8];
      auto loadB = [&](int c, int sl) {
        const _Float16* bp = Wp + (long)c * 4096 + boff;
#pragma unroll
        for (int nt = 0; nt < 8; ++nt) Bb[sl][nt] = *(const h8*)(bp + nt * 512);
      };
      auto loadA = [&](const _Float16* hb, int cloc, int idx) {
        Ab[idx] = vload16(hb + cloc * 2048 + aoff);
      };

      // ---- phase A FIRST: h0(n) part (weights c0..c0+3) — L0 runs ahead,
      // usually ready; hides the h2 recurrent-chain spin behind this GEMM.
      loadB(c0, 0);                                // pre-spin weight prefetch
      if (lane < 4) spin1(fL0 + c0 + lane, n + 1); // h0(n) slices visible
#pragma unroll
      for (int i = 0; i < 4; ++i) loadA(h0cur, c0 + i, i);
#pragma unroll
      for (int i = 0; i < 4; ++i) {
        if (i + 1 < 4) loadB(c0 + i + 1, (i + 1) & 1);
        const h8 A = Ab[i];
#pragma unroll
        for (int nt = 0; nt < 8; ++nt)
          acc[nt] = __builtin_amdgcn_mfma_f32_16x16x32_f16(A, Bb[i & 1][nt], acc[nt], 0, 0, 0);
      }

      // ---- phase B: h2(n-1) part (weights 32+c0..) — the recurrent chain
      loadB(32 + c0, 0);                           // pre-spin weight prefetch
      if (lane < 4) spin1(fL1 + c0 + lane, n);     // h2(n-1) slices visible
#pragma unroll
      for (int i = 0; i < 4; ++i) loadA(h2prev, c0 + i, i);
#pragma unroll
      for (int i = 0; i < 4; ++i) {
        if (i + 1 < 4) loadB(32 + c0 + i + 1, (i + 1) & 1);
        const h8 A = Ab[i];
#pragma unroll
        for (int nt = 0; nt < 8; ++nt)
          acc[nt] = __builtin_amdgcn_mfma_f32_16x16x32_f16(A, Bb[i & 1][nt], acc[nt], 0, 0, 0);
      }
      dump(acc);
      // slot n&1 overwrites h2(n-2): L1 peers (step n-1 phase B) done iff fL1 >= n.
      pointwise_publish(h2q + (n & 1) * 65536, n, n);
    }
  }
}

// ---------------------------------------------------------------------------
__global__ void head_kernel(const _Float16* __restrict__ h2s, const float* __restrict__ Wh,
                            const float* __restrict__ bh, float* __restrict__ out)
{
  const int blk = blockIdx.x;            // 64*24
  const int b = blk / 24, j = blk % 24;
  const int lane = threadIdx.x;          // 64
  float sum = 0.f;
#pragma unroll
  for (int k0 = 0; k0 < 1024; k0 += 64) {
    const int hid = k0 + lane;
    const float hv = (float)h2s[((hid >> 5) * 4 + (b >> 4)) * 512 + (b & 15) * 32 + (hid & 31)];
    sum += hv * Wh[(long)j * 1024 + hid];
  }
#pragma unroll
  for (int off = 32; off > 0; off >>= 1)
    sum += __shfl_down(sum, off, 64);
  if (lane == 0) out[b * 24 + j] = sum + bh[j];
}

// ---------------------------------------------------------------------------
extern "C" void kernel_launch(void* const* d_in, const int* in_sizes, int n_in,
                              void* d_out, int out_size, void* d_ws, size_t ws_size,
                              hipStream_t stream)
{
  const float* x    = (const float*)d_in[0];
  const float* Wih0 = (const float*)d_in[1];
  const float* Whh0 = (const float*)d_in[2];
  const float* bih0 = (const float*)d_in[3];
  const float* bhh0 = (const float*)d_in[4];
  const float* Wih1 = (const float*)d_in[5];
  const float* Whh1 = (const float*)d_in[6];
  const float* bih1 = (const float*)d_in[7];
  const float* bhh1 = (const float*)d_in[8];
  const float* Whd  = (const float*)d_in[9];
  const float* bhd  = (const float*)d_in[10];

  char* ws = (char*)d_ws;
  _Float16* W0p     = (_Float16*)(ws + WS_W0P);
  _Float16* W1p     = (_Float16*)(ws + WS_W1P);
  _Float16* h0q     = (_Float16*)(ws + WS_H0Q);
  _Float16* h2q     = (_Float16*)(ws + WS_H2Q);
  unsigned* sync_ws = (unsigned*)(ws + WS_SYNC);
  float* out = (float*)d_out;

  const bool use_xpk = (ws_size >= WS_XPK_END);
  _Float16* xpk = use_xpk ? (_Float16*)(ws + WS_XPK) : nullptr;

  prep_kernel<<<dim3(2048), dim3(256), 0, stream>>>(
      x, Wih0, Whh0, Wih1, Whh1, W0p, W1p, xpk,
      (unsigned*)(ws + WS_H0Q), sync_ws);

  // static ~3.7 KB + dynamic 98,304 B LDS -> 1 WG/CU -> 256 WGs co-resident.
  if (use_xpk)
    lstm_kernel<true><<<dim3(256), dim3(512), 98304, stream>>>(
        x, xpk, bih0, bhh0, bih1, bhh1, W0p, W1p, h0q, h2q, sync_ws);
  else
    lstm_kernel<false><<<dim3(256), dim3(512), 98304, stream>>>(
        x, nullptr, bih0, bhh0, bih1, bhh1, W0p, W1p, h0q, h2q, sync_ws);

  head_kernel<<<dim3(64 * 24), dim3(64), 0, stream>>>(
      h2q + 65536, Whd, bhd, out);   // h2(511), slot 511&1 = 1
}